// Round 1
// baseline (2606.271 us; speedup 1.0000x reference)
//
#include <hip/hip_runtime.h>
#include <hip/hip_bf16.h>

// ---------------- problem constants ----------------
#define NA 10
#define NB 1024
#define NY 94
#define NR 256
#define NH 128
#define NXD 2
#define NT 50
#define FSC 0.1f
#define NIN 350
#define K1 352            // padded enc K (y+h rounded up to 32)
#define ENC_S 360         // enc LDS row stride (bf16 elems) -> 720B, 16B aligned, 2-way banks
#define H_S 260           // h LDS row stride (fp32)
#define D_S 136           // d1/d2 LDS row stride (bf16) -> 272B, 16B aligned
#define BT 64             // batch rows per block
#define LOG2PI 1.8378770664093453f

typedef __attribute__((ext_vector_type(8))) short frag_b16;
typedef __attribute__((ext_vector_type(4))) float frag_f32;

__device__ __forceinline__ frag_f32 mfma16(frag_b16 a, frag_b16 b, frag_f32 c) {
    return __builtin_amdgcn_mfma_f32_16x16x32_bf16(a, b, c, 0, 0, 0);
}

__device__ __forceinline__ unsigned short f2bf(float f) {
    unsigned int u = __float_as_uint(f);
    u = (u + 0x7fffu + ((u >> 16) & 1u)) >> 16;
    return (unsigned short)u;
}
__device__ __forceinline__ float bf2f(unsigned short h) {
    return __uint_as_float(((unsigned int)h) << 16);
}
__device__ __forceinline__ float sigm(float x) { return 1.f / (1.f + __expf(-x)); }
__device__ __forceinline__ float tanh_c(float x) {
    float xx = fminf(fmaxf(x, -15.f), 15.f);
    float e = __expf(2.f * xx);
    return (e - 1.f) / (e + 1.f);
}
__device__ __forceinline__ float softp(float x) {
    return fmaxf(x, 0.f) + log1pf(__expf(-fabsf(x)));
}

// ---------------- prep kernels ----------------
__global__ void k_convert(const float* __restrict__ src, unsigned short* __restrict__ dst, int n) {
    int i = blockIdx.x * 256 + threadIdx.x;
    if (i < n) dst[i] = f2bf(src[i]);
}

// W_ih (A,768,350) -> Wi (A,768,352) with columns reordered to [h(256) | y(94) | zero pad(2)]
__global__ void k_prep_wi(const float* __restrict__ w_ih, unsigned short* __restrict__ wi) {
    int i = blockIdx.x * 256 + threadIdx.x;
    if (i >= NA * 768 * K1) return;
    int k = i % K1;
    int g = (i / K1) % 768;
    int a = i / (K1 * 768);
    float v = 0.f;
    if (k < 256)       v = w_ih[(size_t)(a * 768 + g) * NIN + NY + k];
    else if (k < 350)  v = w_ih[(size_t)(a * 768 + g) * NIN + (k - 256)];
    wi[i] = f2bf(v);
}

// ---------------- main persistent kernel ----------------
__launch_bounds__(512)
__global__ void k_main(const float* __restrict__ states,
                       const unsigned short* __restrict__ Wi,   // [A][768][352]
                       const unsigned short* __restrict__ Wh,   // [A][768][256]
                       const unsigned short* __restrict__ D1w,  // [A][128][256]
                       const unsigned short* __restrict__ D2w,  // [A][128][128]
                       const float* __restrict__ b_ih, const float* __restrict__ b_hh,
                       const float* __restrict__ d1_b, const float* __restrict__ d2_b,
                       const float* __restrict__ m_w,  const float* __restrict__ m_b,
                       const float* __restrict__ s_w,  const float* __restrict__ s_b,
                       float* __restrict__ out)
{
    __shared__ float          h_lds[BT * H_S];    // 66,560 B (fp32 carry)
    __shared__ unsigned short enc[BT * ENC_S];    // 46,080 B  [h(256)|y(94)|pad]
    __shared__ unsigned short d1buf[BT * D_S];    // 17,408 B
    __shared__ unsigned short d2buf[BT * D_S];    // 17,408 B
    __shared__ float          msbuf[BT * 4];      //  1,024 B

    // XCD-aware swizzle: blocks on one XCD (g%8) cover contiguous (a,btile) range
    const int g  = blockIdx.x;          // 0..159
    const int p  = (g & 7) * 20 + (g >> 3);
    const int a  = p >> 4;              // agent 0..9
    const int b0 = (p & 15) * BT;       // batch tile base

    const int tid  = threadIdx.x;
    const int w    = tid >> 6;          // wave 0..7
    const int lane = tid & 63;
    const int quad = lane >> 4;
    const int l16  = lane & 15;
    const int c0   = w * 32;            // this wave's GRU column range (per gate)
    const int dcol = w * 16;            // this wave's d1/d2 column tile

    const unsigned short* Wia = Wi  + (size_t)a * 768 * K1;
    const unsigned short* Wha = Wh  + (size_t)a * 768 * 256;
    const unsigned short* D1a = D1w + (size_t)a * 128 * 256;
    const unsigned short* D2a = D2w + (size_t)a * 128 * 128;

    for (int i = tid; i < BT * H_S;   i += 512) h_lds[i] = 0.f;
    for (int i = tid; i < BT * ENC_S; i += 512) enc[i] = 0;
    float accL = 0.f, accEp = 0.f, accEv = 0.f;
    __syncthreads();

    const int koff = quad * 8;
    const frag_f32 z4 = {0.f, 0.f, 0.f, 0.f};

    for (int t = 0; t < NT; ++t) {
        // ---- phase 0: stage y_t into enc[:,256:350] ----
        {
            const int row = tid >> 3;
            const int c8  = tid & 7;
            const float* yp = states + (((size_t)t * NA + a) * NB + (b0 + row)) * NY;
            #pragma unroll
            for (int j = 0; j < 12; ++j) {
                int c = c8 * 12 + j;
                if (c < NY) enc[row * ENC_S + 256 + c] = f2bf(yp[c]);
            }
        }
        __syncthreads();

        // ---- phase 1: fused GRU GEMMs (gi+gh for r,z; separate i_n,h_n) + d1 ----
        frag_f32 Ar[4][2], Az[4][2], Ain[4][2], Ahn[4][2], Ad1[4];
        #pragma unroll
        for (int mt = 0; mt < 4; ++mt) {
            #pragma unroll
            for (int nt = 0; nt < 2; ++nt) { Ar[mt][nt]=z4; Az[mt][nt]=z4; Ain[mt][nt]=z4; Ahn[mt][nt]=z4; }
            Ad1[mt] = z4;
        }
        for (int ks = 0; ks < 11; ++ks) {
            const int kk = ks * 32 + koff;
            frag_b16 am[4];
            #pragma unroll
            for (int mt = 0; mt < 4; ++mt)
                am[mt] = *(const frag_b16*)&enc[(mt * 16 + l16) * ENC_S + kk];
            #pragma unroll
            for (int nt = 0; nt < 2; ++nt) {
                const int col = c0 + nt * 16 + l16;
                frag_b16 br = *(const frag_b16*)&Wia[(size_t)(      col) * K1 + kk];
                frag_b16 bz = *(const frag_b16*)&Wia[(size_t)(256 + col) * K1 + kk];
                frag_b16 bn = *(const frag_b16*)&Wia[(size_t)(512 + col) * K1 + kk];
                #pragma unroll
                for (int mt = 0; mt < 4; ++mt) {
                    Ar[mt][nt]  = mfma16(am[mt], br, Ar[mt][nt]);
                    Az[mt][nt]  = mfma16(am[mt], bz, Az[mt][nt]);
                    Ain[mt][nt] = mfma16(am[mt], bn, Ain[mt][nt]);
                }
            }
            if (ks < 8) {
                #pragma unroll
                for (int nt = 0; nt < 2; ++nt) {
                    const int col = c0 + nt * 16 + l16;
                    frag_b16 br = *(const frag_b16*)&Wha[(size_t)(      col) * 256 + kk];
                    frag_b16 bz = *(const frag_b16*)&Wha[(size_t)(256 + col) * 256 + kk];
                    frag_b16 bn = *(const frag_b16*)&Wha[(size_t)(512 + col) * 256 + kk];
                    #pragma unroll
                    for (int mt = 0; mt < 4; ++mt) {
                        Ar[mt][nt]  = mfma16(am[mt], br, Ar[mt][nt]);
                        Az[mt][nt]  = mfma16(am[mt], bz, Az[mt][nt]);
                        Ahn[mt][nt] = mfma16(am[mt], bn, Ahn[mt][nt]);
                    }
                }
                frag_b16 bd = *(const frag_b16*)&D1a[(size_t)(dcol + l16) * 256 + kk];
                #pragma unroll
                for (int mt = 0; mt < 4; ++mt) Ad1[mt] = mfma16(am[mt], bd, Ad1[mt]);
            }
        }
        __syncthreads();   // all reads of enc/h done before updates

        // ---- phase 2: d1 epilogue + GRU gate update (writes h_lds, enc, d1buf) ----
        {
            const float db = d1_b[a * NH + dcol + l16];
            #pragma unroll
            for (int mt = 0; mt < 4; ++mt)
                #pragma unroll
                for (int rg = 0; rg < 4; ++rg) {
                    const int row = mt * 16 + quad * 4 + rg;
                    float v = Ad1[mt][rg] + db;
                    d1buf[row * D_S + dcol + l16] = f2bf(v > 0.f ? v : 0.f);
                }
        }
        #pragma unroll
        for (int nt = 0; nt < 2; ++nt) {
            const int col = c0 + nt * 16 + l16;
            const float brz = b_ih[a * 768 + col]       + b_hh[a * 768 + col];
            const float bzz = b_ih[a * 768 + 256 + col] + b_hh[a * 768 + 256 + col];
            const float bin = b_ih[a * 768 + 512 + col];
            const float bhn = b_hh[a * 768 + 512 + col];
            #pragma unroll
            for (int mt = 0; mt < 4; ++mt)
                #pragma unroll
                for (int rg = 0; rg < 4; ++rg) {
                    const int row = mt * 16 + quad * 4 + rg;
                    float r  = sigm(Ar[mt][nt][rg] + brz);
                    float zz = sigm(Az[mt][nt][rg] + bzz);
                    float nn = tanh_c(Ain[mt][nt][rg] + bin + r * (Ahn[mt][nt][rg] + bhn));
                    float hold = h_lds[row * H_S + col];
                    float hnew = (1.f - zz) * nn + zz * hold;
                    h_lds[row * H_S + col] = hnew;
                    enc[row * ENC_S + col] = f2bf(hnew);
                }
        }
        __syncthreads();

        // ---- phase 3: d2 GEMM (K=128) ----
        frag_f32 Ad2[4];
        #pragma unroll
        for (int mt = 0; mt < 4; ++mt) Ad2[mt] = z4;
        for (int ks = 0; ks < 4; ++ks) {
            const int kk = ks * 32 + koff;
            frag_b16 bd = *(const frag_b16*)&D2a[(size_t)(dcol + l16) * 128 + kk];
            #pragma unroll
            for (int mt = 0; mt < 4; ++mt) {
                frag_b16 am2 = *(const frag_b16*)&d1buf[(mt * 16 + l16) * D_S + kk];
                Ad2[mt] = mfma16(am2, bd, Ad2[mt]);
            }
        }
        {
            const float db = d2_b[a * NH + dcol + l16];
            #pragma unroll
            for (int mt = 0; mt < 4; ++mt)
                #pragma unroll
                for (int rg = 0; rg < 4; ++rg) {
                    const int row = mt * 16 + quad * 4 + rg;
                    float v = Ad2[mt][rg] + db;
                    d2buf[row * D_S + dcol + l16] = f2bf(v > 0.f ? v : 0.f);
                }
        }
        __syncthreads();

        // ---- phase 4: mean/std heads (4 outputs x 64 rows, VALU) ----
        if (tid < 256) {
            const int row = tid >> 2, o = tid & 3;
            const float* wv = (o < 2) ? (m_w + (size_t)(a * NXD + o) * NH)
                                      : (s_w + (size_t)(a * NXD + (o - 2)) * NH);
            float acc = (o < 2) ? m_b[a * NXD + o] : s_b[a * NXD + (o - 2)];
            for (int k = 0; k < NH; ++k)
                acc += bf2f(d2buf[row * D_S + k]) * wv[k];
            msbuf[row * 4 + o] = acc;
        }
        __syncthreads();

        // ---- phase 5: per-row loss terms (threads 0..63) ----
        if (tid < 64) {
            const int row = tid;
            const float* f0 = states + (((size_t)t * NA + a) * NB + (b0 + row)) * NY + 4 * a;
            const float* f1 = states + (((size_t)(t + 1) * NA + a) * NB + (b0 + row)) * NY + 4 * a;
            float p0 = f0[0], p1 = f0[1], v0 = f0[2], v1 = f0[3];
            float q0 = f1[0], q1 = f1[1], x0 = f1[2], x1 = f1[3];
            float mm0 = msbuf[row * 4 + 0], mm1 = msbuf[row * 4 + 1];
            float s0 = softp(msbuf[row * 4 + 2]), s1 = softp(msbuf[row * 4 + 3]);
            float t0 = (x0 - mm0) / s0, t1 = (x1 - mm1) / s1;
            accL += 0.5f * (t0 * t0 + t1 * t1 + 2.f * (__logf(s0) + __logf(s1)) + 2.f * LOG2PI);
            float e0 = p0 + v0 * FSC - q0, e1 = p1 + v1 * FSC - q1;
            accEp += sqrtf(e0 * e0 + e1 * e1);
            float g0 = mm0 - x0, g1 = mm1 - x1;
            accEv += sqrtf(g0 * g0 + g1 * g1);
        }
        __syncthreads();
    }

    // ---- final: wave-0 reduction + one atomicAdd per block ----
    if (tid < 64) {
        float L = accL, E = accEp, V = accEv;
        for (int off = 32; off; off >>= 1) {
            L += __shfl_down(L, off);
            E += __shfl_down(E, off);
            V += __shfl_down(V, off);
        }
        if (tid == 0) {
            const float inv = 1.f / (float)(NT * NA);
            atomicAdd(&out[0], L * inv);
            atomicAdd(&out[1], E * inv);
            atomicAdd(&out[2], V * inv);
        }
    }
}

extern "C" void kernel_launch(void* const* d_in, const int* in_sizes, int n_in,
                              void* d_out, int out_size, void* d_ws, size_t ws_size,
                              hipStream_t stream) {
    const float* states = (const float*)d_in[0];
    const float* w_ih   = (const float*)d_in[1];
    const float* w_hh   = (const float*)d_in[2];
    const float* b_ih   = (const float*)d_in[3];
    const float* b_hh   = (const float*)d_in[4];
    const float* d1_w   = (const float*)d_in[5];
    const float* d1_b   = (const float*)d_in[6];
    const float* d2_w   = (const float*)d_in[7];
    const float* d2_b   = (const float*)d_in[8];
    const float* m_w    = (const float*)d_in[9];
    const float* m_b    = (const float*)d_in[10];
    const float* s_w    = (const float*)d_in[11];
    const float* s_b    = (const float*)d_in[12];

    unsigned short* Wi = (unsigned short*)d_ws;
    unsigned short* Wh = Wi + (size_t)NA * 768 * K1;
    unsigned short* D1 = Wh + (size_t)NA * 768 * 256;
    unsigned short* D2 = D1 + (size_t)NA * 128 * 256;

    hipMemsetAsync(d_out, 0, 3 * sizeof(float), stream);

    const int nwi = NA * 768 * K1;
    k_prep_wi<<<(nwi + 255) / 256, 256, 0, stream>>>(w_ih, Wi);
    const int nwh = NA * 768 * 256;
    k_convert<<<(nwh + 255) / 256, 256, 0, stream>>>(w_hh, Wh, nwh);
    const int nd1 = NA * 128 * 256;
    k_convert<<<(nd1 + 255) / 256, 256, 0, stream>>>(d1_w, D1, nd1);
    const int nd2 = NA * 128 * 128;
    k_convert<<<(nd2 + 255) / 256, 256, 0, stream>>>(d2_w, D2, nd2);

    k_main<<<dim3(160), dim3(512), 0, stream>>>(states, Wi, Wh, D1, D2,
                                                b_ih, b_hh, d1_b, d2_b,
                                                m_w, m_b, s_w, s_b, (float*)d_out);
}

// Round 2
// 2235.919 us; speedup vs baseline: 1.1656x; 1.1656x over previous
//
#include <hip/hip_runtime.h>
#include <hip/hip_bf16.h>

// ---------------- problem constants ----------------
#define NA 10
#define NB 1024
#define NY 94
#define NR 256
#define NH 128
#define NT 50
#define FSC 0.1f
#define NIN 350
#define K1 352            // padded enc K: [h(256) | y(94) | pad(2)]
#define ENC_S 360         // enc LDS row stride (bf16) -> 720B: 2-way banks, 16B aligned
#define D_S 136           // d1/d2 LDS row stride (bf16) -> 272B
#define BT 64             // batch rows per block
#define LOG2PI 1.8378770664093453f

typedef __attribute__((ext_vector_type(8))) short frag_b16;
typedef __attribute__((ext_vector_type(4))) float frag_f32;

__device__ __forceinline__ frag_f32 mfma16(frag_b16 a, frag_b16 b, frag_f32 c) {
    return __builtin_amdgcn_mfma_f32_16x16x32_bf16(a, b, c, 0, 0, 0);
}
__device__ __forceinline__ unsigned short f2bf(float f) {
    unsigned int u = __float_as_uint(f);
    u = (u + 0x7fffu + ((u >> 16) & 1u)) >> 16;
    return (unsigned short)u;
}
__device__ __forceinline__ float bf2f(unsigned short h) {
    return __uint_as_float(((unsigned int)h) << 16);
}
__device__ __forceinline__ float sigm(float x) { return 1.f / (1.f + __expf(-x)); }
__device__ __forceinline__ float tanh_c(float x) {
    float xx = fminf(fmaxf(x, -15.f), 15.f);
    float e = __expf(2.f * xx);
    return (e - 1.f) / (e + 1.f);
}
__device__ __forceinline__ float softp(float x) {
    return fmaxf(x, 0.f) + log1pf(__expf(-fabsf(x)));
}

// ---------------- prep kernels ----------------
// Wrz [A][512][352]: rows 0..255 = r, 256..511 = z. cols [h|y|pad].
// For k<256 (h part) the W_hh row is pre-added (gi+gh fusion for r,z).
__global__ void k_prep_wrz(const float* __restrict__ w_ih, const float* __restrict__ w_hh,
                           unsigned short* __restrict__ dst) {
    int i = blockIdx.x * 256 + threadIdx.x;
    if (i >= NA * 512 * K1) return;
    int k = i % K1;
    int g = (i / K1) % 512;
    int a = i / (K1 * 512);
    float v = 0.f;
    if (k < 256)      v = w_ih[(size_t)(a * 768 + g) * NIN + NY + k] + w_hh[(size_t)(a * 768 + g) * NR + k];
    else if (k < 350) v = w_ih[(size_t)(a * 768 + g) * NIN + (k - 256)];
    dst[i] = f2bf(v);
}
// Wni [A][256][352]: i_n rows (768-row index 512..767), cols [h|y|pad]
__global__ void k_prep_wni(const float* __restrict__ w_ih, unsigned short* __restrict__ dst) {
    int i = blockIdx.x * 256 + threadIdx.x;
    if (i >= NA * 256 * K1) return;
    int k = i % K1;
    int g = (i / K1) % 256;
    int a = i / (K1 * 256);
    float v = 0.f;
    if (k < 256)      v = w_ih[(size_t)(a * 768 + 512 + g) * NIN + NY + k];
    else if (k < 350) v = w_ih[(size_t)(a * 768 + 512 + g) * NIN + (k - 256)];
    dst[i] = f2bf(v);
}
// Wnh [A][256][256]: h_n rows
__global__ void k_prep_wnh(const float* __restrict__ w_hh, unsigned short* __restrict__ dst) {
    int i = blockIdx.x * 256 + threadIdx.x;
    if (i >= NA * 256 * NR) return;
    int k = i % NR;
    int g = (i / NR) % 256;
    int a = i / (NR * 256);
    dst[i] = f2bf(w_hh[(size_t)(a * 768 + 512 + g) * NR + k]);
}
__global__ void k_convert(const float* __restrict__ src, unsigned short* __restrict__ dst, int n) {
    int i = blockIdx.x * 256 + threadIdx.x;
    if (i < n) dst[i] = f2bf(src[i]);
}

// ---------------- main persistent kernel ----------------
__launch_bounds__(512)
__global__ void k_main(const float* __restrict__ states,
                       const unsigned short* __restrict__ Wrz,  // [A][512][352]
                       const unsigned short* __restrict__ Wni,  // [A][256][352]
                       const unsigned short* __restrict__ Wnh,  // [A][256][256]
                       const unsigned short* __restrict__ D1w,  // [A][128][256]
                       const unsigned short* __restrict__ D2w,  // [A][128][128]
                       const float* __restrict__ b_ih, const float* __restrict__ b_hh,
                       const float* __restrict__ d1_b, const float* __restrict__ d2_b,
                       const float* __restrict__ m_w,  const float* __restrict__ m_b,
                       const float* __restrict__ s_w,  const float* __restrict__ s_b,
                       float* __restrict__ out)
{
    __shared__ unsigned short enc[2][BT * ENC_S]; // 2 x 46,080 B, [h(256)|y(94)|pad]
    __shared__ unsigned short d1buf[BT * D_S];    // 17,408 B
    __shared__ unsigned short d2buf[BT * D_S];    // 17,408 B

    // XCD-aware swizzle: blocks with same (g&7) share <=2 agents' weights in L2
    const int g  = blockIdx.x;
    const int p  = (g & 7) * 20 + (g >> 3);
    const int a  = p >> 4;
    const int b0 = (p & 15) * BT;

    const int tid  = threadIdx.x;
    const int w    = tid >> 6;
    const int lane = tid & 63;
    const int quad = lane >> 4;
    const int l16  = lane & 15;
    const int c0   = w * 32;            // wave's GRU column slice (per gate)
    const int dcol = w * 16;            // wave's d1/d2 column tile
    const int koff = quad * 8;

    const unsigned short* Wrza = Wrz + (size_t)a * 512 * K1;
    const unsigned short* Wnia = Wni + (size_t)a * 256 * K1;
    const unsigned short* Wnha = Wnh + (size_t)a * 256 * NR;
    const unsigned short* D1a  = D1w + (size_t)a * NH * NR;
    const unsigned short* D2a  = D2w + (size_t)a * NH * NH;

    for (int i = tid; i < BT * ENC_S; i += 512) { enc[0][i] = 0; enc[1][i] = 0; }
    __syncthreads();
    // stage y_0 into enc[0]
    {
        const int row = tid >> 3, c8 = tid & 7;
        const float* yp = states + (((size_t)0 * NA + a) * NB + (b0 + row)) * NY;
        #pragma unroll
        for (int j = 0; j < 12; ++j) {
            int c = c8 * 12 + j;
            if (c < NY) enc[0][row * ENC_S + 256 + c] = f2bf(yp[c]);
        }
    }
    float accL = 0.f, accEp = 0.f, accEv = 0.f;
    __syncthreads();

    const frag_f32 z4 = {0.f, 0.f, 0.f, 0.f};

    for (int t = 0; t < NT; ++t) {
        unsigned short* cur = enc[t & 1];
        unsigned short* nxt = enc[(t + 1) & 1];

        // ============ pass A: combined rz GEMM (K=352) + d1 GEMM (K=256) ============
        frag_f32 Cr[4][2], Cz[4][2], Cd1[4];
        #pragma unroll
        for (int mt = 0; mt < 4; ++mt) {
            #pragma unroll
            for (int nt = 0; nt < 2; ++nt) { Cr[mt][nt] = z4; Cz[mt][nt] = z4; }
            Cd1[mt] = z4;
        }
        frag_b16 bR[2][2], bZ[2][2], bD1[2];
        {
            const int kk = koff;
            #pragma unroll
            for (int nt = 0; nt < 2; ++nt) {
                bR[0][nt] = *(const frag_b16*)&Wrza[(size_t)(      c0 + nt * 16 + l16) * K1 + kk];
                bZ[0][nt] = *(const frag_b16*)&Wrza[(size_t)(256 + c0 + nt * 16 + l16) * K1 + kk];
            }
            bD1[0] = *(const frag_b16*)&D1a[(size_t)(dcol + l16) * NR + kk];
        }
        for (int ks = 0; ks < 11; ++ks) {
            const int cb = ks & 1, nb = cb ^ 1;
            if (ks < 10) {
                const int kk = (ks + 1) * 32 + koff;
                #pragma unroll
                for (int nt = 0; nt < 2; ++nt) {
                    bR[nb][nt] = *(const frag_b16*)&Wrza[(size_t)(      c0 + nt * 16 + l16) * K1 + kk];
                    bZ[nb][nt] = *(const frag_b16*)&Wrza[(size_t)(256 + c0 + nt * 16 + l16) * K1 + kk];
                }
                if (ks + 1 < 8) bD1[nb] = *(const frag_b16*)&D1a[(size_t)(dcol + l16) * NR + kk];
            }
            const int kk = ks * 32 + koff;
            frag_b16 am[4];
            #pragma unroll
            for (int mt = 0; mt < 4; ++mt)
                am[mt] = *(const frag_b16*)&cur[(mt * 16 + l16) * ENC_S + kk];
            #pragma unroll
            for (int nt = 0; nt < 2; ++nt)
                #pragma unroll
                for (int mt = 0; mt < 4; ++mt) {
                    Cr[mt][nt] = mfma16(am[mt], bR[cb][nt], Cr[mt][nt]);
                    Cz[mt][nt] = mfma16(am[mt], bZ[cb][nt], Cz[mt][nt]);
                }
            if (ks < 8) {
                #pragma unroll
                for (int mt = 0; mt < 4; ++mt) Cd1[mt] = mfma16(am[mt], bD1[cb], Cd1[mt]);
            }
        }
        // ---- epilogue A: d1 relu store; r,z -> sigmoid, kept in regs ----
        {
            const float db = d1_b[a * NH + dcol + l16];
            #pragma unroll
            for (int mt = 0; mt < 4; ++mt)
                #pragma unroll
                for (int rg = 0; rg < 4; ++rg) {
                    const int row = mt * 16 + quad * 4 + rg;
                    float v = Cd1[mt][rg] + db;
                    d1buf[row * D_S + dcol + l16] = f2bf(v > 0.f ? v : 0.f);
                }
        }
        #pragma unroll
        for (int nt = 0; nt < 2; ++nt) {
            const int col = c0 + nt * 16 + l16;
            const float brz = b_ih[a * 768 + col]       + b_hh[a * 768 + col];
            const float bzz = b_ih[a * 768 + 256 + col] + b_hh[a * 768 + 256 + col];
            #pragma unroll
            for (int mt = 0; mt < 4; ++mt)
                #pragma unroll
                for (int rg = 0; rg < 4; ++rg) {
                    Cr[mt][nt][rg] = sigm(Cr[mt][nt][rg] + brz);
                    Cz[mt][nt][rg] = sigm(Cz[mt][nt][rg] + bzz);
                }
        }

        // ============ pass B: i_n (K=352) + h_n (K=256) GEMMs ============
        frag_f32 Ci[4][2], Ch[4][2];
        #pragma unroll
        for (int mt = 0; mt < 4; ++mt)
            #pragma unroll
            for (int nt = 0; nt < 2; ++nt) { Ci[mt][nt] = z4; Ch[mt][nt] = z4; }
        frag_b16 bI[2][2], bH[2][2];
        {
            const int kk = koff;
            #pragma unroll
            for (int nt = 0; nt < 2; ++nt) {
                bI[0][nt] = *(const frag_b16*)&Wnia[(size_t)(c0 + nt * 16 + l16) * K1 + kk];
                bH[0][nt] = *(const frag_b16*)&Wnha[(size_t)(c0 + nt * 16 + l16) * NR + kk];
            }
        }
        for (int ks = 0; ks < 11; ++ks) {
            const int cb = ks & 1, nb = cb ^ 1;
            if (ks < 10) {
                const int kk = (ks + 1) * 32 + koff;
                #pragma unroll
                for (int nt = 0; nt < 2; ++nt) {
                    bI[nb][nt] = *(const frag_b16*)&Wnia[(size_t)(c0 + nt * 16 + l16) * K1 + kk];
                    if (ks + 1 < 8)
                        bH[nb][nt] = *(const frag_b16*)&Wnha[(size_t)(c0 + nt * 16 + l16) * NR + kk];
                }
            }
            const int kk = ks * 32 + koff;
            frag_b16 am[4];
            #pragma unroll
            for (int mt = 0; mt < 4; ++mt)
                am[mt] = *(const frag_b16*)&cur[(mt * 16 + l16) * ENC_S + kk];
            #pragma unroll
            for (int nt = 0; nt < 2; ++nt)
                #pragma unroll
                for (int mt = 0; mt < 4; ++mt) {
                    Ci[mt][nt] = mfma16(am[mt], bI[cb][nt], Ci[mt][nt]);
                    if (ks < 8) Ch[mt][nt] = mfma16(am[mt], bH[cb][nt], Ch[mt][nt]);
                }
        }
        // ---- epilogue B: gates, h update (bf16 carry), write h_new to nxt ----
        #pragma unroll
        for (int nt = 0; nt < 2; ++nt) {
            const int col = c0 + nt * 16 + l16;
            const float bin = b_ih[a * 768 + 512 + col];
            const float bhn = b_hh[a * 768 + 512 + col];
            #pragma unroll
            for (int mt = 0; mt < 4; ++mt)
                #pragma unroll
                for (int rg = 0; rg < 4; ++rg) {
                    const int row = mt * 16 + quad * 4 + rg;
                    const float r = Cr[mt][nt][rg];
                    const float z = Cz[mt][nt][rg];
                    const float n = tanh_c(Ci[mt][nt][rg] + bin + r * (Ch[mt][nt][rg] + bhn));
                    const float hold = bf2f(cur[row * ENC_S + col]);
                    const float hnew = (1.f - z) * n + z * hold;
                    nxt[row * ENC_S + col] = f2bf(hnew);
                }
        }
        // ---- stage y_{t+1} into nxt (states has T+1 slots; t+1 <= 50 valid) ----
        {
            const int row = tid >> 3, c8 = tid & 7;
            const float* yp = states + (((size_t)(t + 1) * NA + a) * NB + (b0 + row)) * NY;
            #pragma unroll
            for (int j = 0; j < 12; ++j) {
                int c = c8 * 12 + j;
                if (c < NY) nxt[row * ENC_S + 256 + c] = f2bf(yp[c]);
            }
        }
        __syncthreads();   // barrier 1 of 2

        // ============ pass C: d2 GEMM (K=128) ============
        frag_f32 Cd2[4];
        #pragma unroll
        for (int mt = 0; mt < 4; ++mt) Cd2[mt] = z4;
        for (int ks = 0; ks < 4; ++ks) {
            const int kk = ks * 32 + koff;
            frag_b16 bd = *(const frag_b16*)&D2a[(size_t)(dcol + l16) * NH + kk];
            #pragma unroll
            for (int mt = 0; mt < 4; ++mt) {
                frag_b16 am2 = *(const frag_b16*)&d1buf[(mt * 16 + l16) * D_S + kk];
                Cd2[mt] = mfma16(am2, bd, Cd2[mt]);
            }
        }
        {
            const float db = d2_b[a * NH + dcol + l16];
            #pragma unroll
            for (int mt = 0; mt < 4; ++mt)
                #pragma unroll
                for (int rg = 0; rg < 4; ++rg) {
                    const int row = mt * 16 + quad * 4 + rg;
                    float v = Cd2[mt][rg] + db;
                    d2buf[row * D_S + dcol + l16] = f2bf(v > 0.f ? v : 0.f);
                }
        }
        __syncthreads();   // barrier 2 of 2

        // ============ heads + loss: waves 0-3; waves 4-7 run ahead ============
        if (tid < 256) {
            const int row = tid >> 2, o = tid & 3;
            const float* wv = (o < 2) ? (m_w + (size_t)(a * 2 + o) * NH)
                                      : (s_w + (size_t)(a * 2 + (o - 2)) * NH);
            float acc = (o < 2) ? m_b[a * 2 + o] : s_b[a * 2 + (o - 2)];
            const unsigned short* dp = &d2buf[row * D_S];
            #pragma unroll
            for (int kb = 0; kb < 16; ++kb) {
                frag_b16 dv = *(const frag_b16*)&dp[kb * 8];
                #pragma unroll
                for (int j = 0; j < 8; ++j)
                    acc += bf2f((unsigned short)dv[j]) * wv[kb * 8 + j];
            }
            const float v1 = __shfl_xor(acc, 1);
            const float v2 = __shfl_xor(acc, 2);
            const float v3 = __shfl_xor(acc, 3);
            if (o == 0) {
                const float* f0 = states + (((size_t)t * NA + a) * NB + (b0 + row)) * NY + 4 * a;
                const float* f1 = states + (((size_t)(t + 1) * NA + a) * NB + (b0 + row)) * NY + 4 * a;
                const float mm0 = acc, mm1 = v1;
                const float s0 = softp(v2), s1 = softp(v3);
                const float x0 = f1[2], x1 = f1[3];
                const float t0 = (x0 - mm0) / s0, t1 = (x1 - mm1) / s1;
                accL += 0.5f * (t0 * t0 + t1 * t1 + 2.f * (__logf(s0) + __logf(s1)) + 2.f * LOG2PI);
                const float e0 = f0[0] + f0[2] * FSC - f1[0];
                const float e1 = f0[1] + f0[3] * FSC - f1[1];
                accEp += sqrtf(e0 * e0 + e1 * e1);
                const float g0 = mm0 - x0, g1 = mm1 - x1;
                accEv += sqrtf(g0 * g0 + g1 * g1);
            }
        }
    }

    // ---- final reduction: only waves 0-3 hold nonzero accs (lanes tid%4==0) ----
    if (tid < 256) {
        float L = accL, E = accEp, V = accEv;
        #pragma unroll
        for (int off = 32; off; off >>= 1) {
            L += __shfl_down(L, off);
            E += __shfl_down(E, off);
            V += __shfl_down(V, off);
        }
        if ((tid & 63) == 0) {
            const float inv = 1.f / (float)(NT * NA);
            atomicAdd(&out[0], L * inv);
            atomicAdd(&out[1], E * inv);
            atomicAdd(&out[2], V * inv);
        }
    }
}

extern "C" void kernel_launch(void* const* d_in, const int* in_sizes, int n_in,
                              void* d_out, int out_size, void* d_ws, size_t ws_size,
                              hipStream_t stream) {
    const float* states = (const float*)d_in[0];
    const float* w_ih   = (const float*)d_in[1];
    const float* w_hh   = (const float*)d_in[2];
    const float* b_ih   = (const float*)d_in[3];
    const float* b_hh   = (const float*)d_in[4];
    const float* d1_w   = (const float*)d_in[5];
    const float* d1_b   = (const float*)d_in[6];
    const float* d2_w   = (const float*)d_in[7];
    const float* d2_b   = (const float*)d_in[8];
    const float* m_w    = (const float*)d_in[9];
    const float* m_b    = (const float*)d_in[10];
    const float* s_w    = (const float*)d_in[11];
    const float* s_b    = (const float*)d_in[12];

    unsigned short* Wrz = (unsigned short*)d_ws;
    unsigned short* Wni = Wrz + (size_t)NA * 512 * K1;
    unsigned short* Wnh = Wni + (size_t)NA * 256 * K1;
    unsigned short* D1  = Wnh + (size_t)NA * 256 * NR;
    unsigned short* D2  = D1  + (size_t)NA * NH * NR;

    hipMemsetAsync(d_out, 0, 3 * sizeof(float), stream);

    const int nrz = NA * 512 * K1;
    k_prep_wrz<<<(nrz + 255) / 256, 256, 0, stream>>>(w_ih, w_hh, Wrz);
    const int nni = NA * 256 * K1;
    k_prep_wni<<<(nni + 255) / 256, 256, 0, stream>>>(w_ih, Wni);
    const int nnh = NA * 256 * NR;
    k_prep_wnh<<<(nnh + 255) / 256, 256, 0, stream>>>(w_hh, Wnh);
    const int nd1 = NA * NH * NR;
    k_convert<<<(nd1 + 255) / 256, 256, 0, stream>>>(d1_w, D1, nd1);
    const int nd2 = NA * NH * NH;
    k_convert<<<(nd2 + 255) / 256, 256, 0, stream>>>(d2_w, D2, nd2);

    k_main<<<dim3(160), dim3(512), 0, stream>>>(states, Wrz, Wni, Wnh, D1, D2,
                                                b_ih, b_hh, d1_b, d2_b,
                                                m_w, m_b, s_w, s_b, (float*)d_out);
}

// Round 3
// 1750.114 us; speedup vs baseline: 1.4892x; 1.2776x over previous
//
#include <hip/hip_runtime.h>
#include <hip/hip_bf16.h>

// ---------------- problem constants ----------------
#define NA 10
#define NB 1024
#define NY 94
#define NR 256
#define NH 128
#define NT 50
#define FSC 0.1f
#define NIN 350
#define K1 352            // padded enc K: [h(256) | y(94) | pad(2)]
#define ENC_S 376         // enc LDS row stride (bf16): 188 dwords, 188%32=28 -> uniform banks for b128
#define D_S 136           // d1/d2 LDS row stride (bf16) -> 272B
#define BT 64             // batch rows per block
#define LOG2PI 1.8378770664093453f

typedef __attribute__((ext_vector_type(8))) short frag_b16;
typedef __attribute__((ext_vector_type(4))) float frag_f32;

__device__ __forceinline__ frag_f32 mfma16(frag_b16 a, frag_b16 b, frag_f32 c) {
    return __builtin_amdgcn_mfma_f32_16x16x32_bf16(a, b, c, 0, 0, 0);
}
__device__ __forceinline__ unsigned short f2bf(float f) {
    unsigned int u = __float_as_uint(f);
    u = (u + 0x7fffu + ((u >> 16) & 1u)) >> 16;
    return (unsigned short)u;
}
__device__ __forceinline__ float bf2f(unsigned short h) {
    return __uint_as_float(((unsigned int)h) << 16);
}
__device__ __forceinline__ float sigm(float x) { return 1.f / (1.f + __expf(-x)); }
__device__ __forceinline__ float tanh_c(float x) {
    float xx = fminf(fmaxf(x, -15.f), 15.f);
    float e = __expf(2.f * xx);
    return (e - 1.f) / (e + 1.f);
}
__device__ __forceinline__ float softp(float x) {
    return fmaxf(x, 0.f) + log1pf(__expf(-fabsf(x)));
}

// ---------------- prep kernels ----------------
// Wrz [A][512][352]: rows 0..255 = r, 256..511 = z. cols [h|y|pad]; h-part has W_hh pre-added.
__global__ void k_prep_wrz(const float* __restrict__ w_ih, const float* __restrict__ w_hh,
                           unsigned short* __restrict__ dst) {
    int i = blockIdx.x * 256 + threadIdx.x;
    if (i >= NA * 512 * K1) return;
    int k = i % K1;
    int g = (i / K1) % 512;
    int a = i / (K1 * 512);
    float v = 0.f;
    if (k < 256)      v = w_ih[(size_t)(a * 768 + g) * NIN + NY + k] + w_hh[(size_t)(a * 768 + g) * NR + k];
    else if (k < 350) v = w_ih[(size_t)(a * 768 + g) * NIN + (k - 256)];
    dst[i] = f2bf(v);
}
// Wni [A][256][352]: i_n rows, cols [h|y|pad]
__global__ void k_prep_wni(const float* __restrict__ w_ih, unsigned short* __restrict__ dst) {
    int i = blockIdx.x * 256 + threadIdx.x;
    if (i >= NA * 256 * K1) return;
    int k = i % K1;
    int g = (i / K1) % 256;
    int a = i / (K1 * 256);
    float v = 0.f;
    if (k < 256)      v = w_ih[(size_t)(a * 768 + 512 + g) * NIN + NY + k];
    else if (k < 350) v = w_ih[(size_t)(a * 768 + 512 + g) * NIN + (k - 256)];
    dst[i] = f2bf(v);
}
// Wnh [A][256][256]: h_n rows
__global__ void k_prep_wnh(const float* __restrict__ w_hh, unsigned short* __restrict__ dst) {
    int i = blockIdx.x * 256 + threadIdx.x;
    if (i >= NA * 256 * NR) return;
    int k = i % NR;
    int g = (i / NR) % 256;
    int a = i / (NR * 256);
    dst[i] = f2bf(w_hh[(size_t)(a * 768 + 512 + g) * NR + k]);
}
__global__ void k_convert(const float* __restrict__ src, unsigned short* __restrict__ dst, int n) {
    int i = blockIdx.x * 256 + threadIdx.x;
    if (i < n) dst[i] = f2bf(src[i]);
}

// ---------------- main persistent kernel ----------------
// 1024 threads = 16 waves (4/SIMD). Wave w owns GRU cols [w*16, w*16+16) of each gate.
__launch_bounds__(1024, 4)
__global__ void k_main(const float* __restrict__ states,
                       const unsigned short* __restrict__ Wrz,  // [A][512][352]
                       const unsigned short* __restrict__ Wni,  // [A][256][352]
                       const unsigned short* __restrict__ Wnh,  // [A][256][256]
                       const unsigned short* __restrict__ D1w,  // [A][128][256]
                       const unsigned short* __restrict__ D2w,  // [A][128][128]
                       const float* __restrict__ b_ih, const float* __restrict__ b_hh,
                       const float* __restrict__ d1_b, const float* __restrict__ d2_b,
                       const float* __restrict__ m_w,  const float* __restrict__ m_b,
                       const float* __restrict__ s_w,  const float* __restrict__ s_b,
                       int* __restrict__ ctrl,
                       float* __restrict__ out)
{
    __shared__ unsigned short enc[2][BT * ENC_S]; // 96,256 B, [h(256)|y(94)|pad]
    __shared__ unsigned short d1buf[BT * D_S];    // 17,408 B
    __shared__ unsigned short d2buf[BT * D_S];    // 17,408 B
    __shared__ float wls[4 * NH];                 //  2,048 B head weights
    __shared__ int s_p;

    const int tid = threadIdx.x;

    // ---- XCD-measured work assignment: agent locality per ACTUAL XCD ----
    if (tid == 0) {
        // s_getreg_b32 hwreg(HW_REG_XCC_ID=20, 0, 32)
        unsigned int xcc = __builtin_amdgcn_s_getreg(63508) & 7u;
        int slot = atomicAdd(&ctrl[xcc], 1);
        int p = -1;
        if (slot < 20) {
            int cand = (int)xcc * 20 + slot;
            if (atomicCAS(&ctrl[16 + cand], 0, 1) == 0) p = cand;
        }
        for (int i = 0; p < 0 && i < 160; ++i) {
            int cand = ((int)xcc * 20 + i) % 160;
            if (atomicCAS(&ctrl[16 + cand], 0, 1) == 0) p = cand;
        }
        s_p = p;
    }
    for (int i = tid; i < BT * ENC_S; i += 1024) { enc[0][i] = 0; enc[1][i] = 0; }
    __syncthreads();

    const int p  = s_p;                 // 0..159; [xcd*20, xcd*20+19] on this XCD
    const int a  = p >> 4;              // agent
    const int b0 = (p & 15) * BT;       // batch tile base

    const int w    = tid >> 6;
    const int lane = tid & 63;
    const int quad = lane >> 4;
    const int l16  = lane & 15;
    const int c0   = w * 16;            // wave's 16-col slice per gate
    const int koff = quad * 8;

    const unsigned short* Wrza = Wrz + (size_t)a * 512 * K1;
    const unsigned short* Wnia = Wni + (size_t)a * 256 * K1;
    const unsigned short* Wnha = Wnh + (size_t)a * 256 * NR;
    const unsigned short* D1a  = D1w + (size_t)a * NH * NR;
    const unsigned short* D2a  = D2w + (size_t)a * NH * NH;

    // stage head weights to LDS once
    if (tid < 512) {
        int o = tid >> 7, k = tid & 127;
        wls[tid] = (o < 2) ? m_w[(size_t)(a * 2 + o) * NH + k]
                           : s_w[(size_t)(a * 2 + (o - 2)) * NH + k];
    }
    // stage y_0 into enc[0]
    {
        const int row = tid >> 4, c16 = tid & 15;
        const float* yp = states + (((size_t)0 * NA + a) * NB + (b0 + row)) * NY;
        #pragma unroll
        for (int j = 0; j < 6; ++j) {
            int c = c16 * 6 + j;
            if (c < NY) enc[0][row * ENC_S + 256 + c] = f2bf(yp[c]);
        }
    }
    float accL = 0.f, accEp = 0.f, accEv = 0.f;
    __syncthreads();

    const frag_f32 z4 = {0.f, 0.f, 0.f, 0.f};

    for (int t = 0; t < NT; ++t) {
        unsigned short* cur = enc[t & 1];
        unsigned short* nxt = enc[(t + 1) & 1];

        // ============ pass A: rz GEMM (K=352) + d1 GEMM (K=256, waves 0-7) ============
        frag_f32 Cr[4], Cz[4], Cd1[4];
        #pragma unroll
        for (int mt = 0; mt < 4; ++mt) { Cr[mt] = z4; Cz[mt] = z4; Cd1[mt] = z4; }
        frag_b16 bR[2], bZ[2], bD1[2];
        bR[0] = *(const frag_b16*)&Wrza[(size_t)(      c0 + l16) * K1 + koff];
        bZ[0] = *(const frag_b16*)&Wrza[(size_t)(256 + c0 + l16) * K1 + koff];
        if (w < 8) bD1[0] = *(const frag_b16*)&D1a[(size_t)(c0 + l16) * NR + koff];
        for (int ks = 0; ks < 11; ++ks) {
            const int cb = ks & 1, nb = cb ^ 1;
            if (ks < 10) {
                const int kk = (ks + 1) * 32 + koff;
                bR[nb] = *(const frag_b16*)&Wrza[(size_t)(      c0 + l16) * K1 + kk];
                bZ[nb] = *(const frag_b16*)&Wrza[(size_t)(256 + c0 + l16) * K1 + kk];
                if (w < 8 && ks < 7) bD1[nb] = *(const frag_b16*)&D1a[(size_t)(c0 + l16) * NR + kk];
            }
            const int kk = ks * 32 + koff;
            frag_b16 am[4];
            #pragma unroll
            for (int mt = 0; mt < 4; ++mt)
                am[mt] = *(const frag_b16*)&cur[(mt * 16 + l16) * ENC_S + kk];
            #pragma unroll
            for (int mt = 0; mt < 4; ++mt) {
                Cr[mt] = mfma16(am[mt], bR[cb], Cr[mt]);
                Cz[mt] = mfma16(am[mt], bZ[cb], Cz[mt]);
            }
            if (w < 8 && ks < 8) {
                #pragma unroll
                for (int mt = 0; mt < 4; ++mt) Cd1[mt] = mfma16(am[mt], bD1[cb], Cd1[mt]);
            }
        }
        // ---- epilogue A: d1 relu store; r,z -> sigmoid in regs ----
        if (w < 8) {
            const float db = d1_b[a * NH + c0 + l16];
            #pragma unroll
            for (int mt = 0; mt < 4; ++mt)
                #pragma unroll
                for (int rg = 0; rg < 4; ++rg) {
                    const int row = mt * 16 + quad * 4 + rg;
                    float v = Cd1[mt][rg] + db;
                    d1buf[row * D_S + c0 + l16] = f2bf(v > 0.f ? v : 0.f);
                }
        }
        {
            const int col = c0 + l16;
            const float brz = b_ih[a * 768 + col]       + b_hh[a * 768 + col];
            const float bzz = b_ih[a * 768 + 256 + col] + b_hh[a * 768 + 256 + col];
            #pragma unroll
            for (int mt = 0; mt < 4; ++mt)
                #pragma unroll
                for (int rg = 0; rg < 4; ++rg) {
                    Cr[mt][rg] = sigm(Cr[mt][rg] + brz);
                    Cz[mt][rg] = sigm(Cz[mt][rg] + bzz);
                }
        }

        // ============ pass B: i_n (K=352) + h_n (K=256) ============
        frag_f32 Ci[4], Ch[4];
        #pragma unroll
        for (int mt = 0; mt < 4; ++mt) { Ci[mt] = z4; Ch[mt] = z4; }
        frag_b16 bI[2], bH[2];
        bI[0] = *(const frag_b16*)&Wnia[(size_t)(c0 + l16) * K1 + koff];
        bH[0] = *(const frag_b16*)&Wnha[(size_t)(c0 + l16) * NR + koff];
        for (int ks = 0; ks < 11; ++ks) {
            const int cb = ks & 1, nb = cb ^ 1;
            if (ks < 10) {
                const int kk = (ks + 1) * 32 + koff;
                bI[nb] = *(const frag_b16*)&Wnia[(size_t)(c0 + l16) * K1 + kk];
                if (ks < 7) bH[nb] = *(const frag_b16*)&Wnha[(size_t)(c0 + l16) * NR + kk];
            }
            const int kk = ks * 32 + koff;
            frag_b16 am[4];
            #pragma unroll
            for (int mt = 0; mt < 4; ++mt)
                am[mt] = *(const frag_b16*)&cur[(mt * 16 + l16) * ENC_S + kk];
            #pragma unroll
            for (int mt = 0; mt < 4; ++mt) {
                Ci[mt] = mfma16(am[mt], bI[cb], Ci[mt]);
                if (ks < 8) Ch[mt] = mfma16(am[mt], bH[cb], Ch[mt]);
            }
        }
        // ---- epilogue B: gates, h update (bf16 carry), write h_new to nxt ----
        {
            const int col = c0 + l16;
            const float bin = b_ih[a * 768 + 512 + col];
            const float bhn = b_hh[a * 768 + 512 + col];
            #pragma unroll
            for (int mt = 0; mt < 4; ++mt)
                #pragma unroll
                for (int rg = 0; rg < 4; ++rg) {
                    const int row = mt * 16 + quad * 4 + rg;
                    const float r = Cr[mt][rg];
                    const float z = Cz[mt][rg];
                    const float n = tanh_c(Ci[mt][rg] + bin + r * (Ch[mt][rg] + bhn));
                    const float hold = bf2f(cur[row * ENC_S + col]);
                    const float hnew = (1.f - z) * n + z * hold;
                    nxt[row * ENC_S + col] = f2bf(hnew);
                }
        }
        // ---- stage y_{t+1} into nxt ----
        {
            const int row = tid >> 4, c16 = tid & 15;
            const float* yp = states + (((size_t)(t + 1) * NA + a) * NB + (b0 + row)) * NY;
            #pragma unroll
            for (int j = 0; j < 6; ++j) {
                int c = c16 * 6 + j;
                if (c < NY) nxt[row * ENC_S + 256 + c] = f2bf(yp[c]);
            }
        }
        // ---- prefetch d2 weights (global only, no LDS dependency) ----
        const int dcol2 = (w >> 1) * 16;     // d2 col tile
        const int m0    = (w & 1) * 2;       // d2 row-half (mt pair)
        frag_b16 bD2[4];
        #pragma unroll
        for (int ks = 0; ks < 4; ++ks)
            bD2[ks] = *(const frag_b16*)&D2a[(size_t)(dcol2 + l16) * NH + ks * 32 + koff];
        __syncthreads();   // barrier 1 of 2

        // ============ pass C: d2 GEMM (K=128), split across all 16 waves ============
        frag_f32 Cd2[2] = {z4, z4};
        #pragma unroll
        for (int ks = 0; ks < 4; ++ks) {
            #pragma unroll
            for (int mi = 0; mi < 2; ++mi) {
                frag_b16 am2 = *(const frag_b16*)&d1buf[((m0 + mi) * 16 + l16) * D_S + ks * 32 + koff];
                Cd2[mi] = mfma16(am2, bD2[ks], Cd2[mi]);
            }
        }
        {
            const float db = d2_b[a * NH + dcol2 + l16];
            #pragma unroll
            for (int mi = 0; mi < 2; ++mi)
                #pragma unroll
                for (int rg = 0; rg < 4; ++rg) {
                    const int row = (m0 + mi) * 16 + quad * 4 + rg;
                    float v = Cd2[mi][rg] + db;
                    d2buf[row * D_S + dcol2 + l16] = f2bf(v > 0.f ? v : 0.f);
                }
        }
        __syncthreads();   // barrier 2 of 2

        // ============ heads + loss: waves 0-3; waves 4-15 run ahead ============
        if (tid < 256) {
            const int row = tid >> 2, o = tid & 3;
            float acc = (o < 2) ? m_b[a * 2 + o] : s_b[a * 2 + (o - 2)];
            const unsigned short* dp = &d2buf[row * D_S];
            const float* wp = &wls[o * NH];
            #pragma unroll
            for (int kb = 0; kb < 16; ++kb) {
                frag_b16 dv = *(const frag_b16*)&dp[kb * 8];
                float4 w0 = *(const float4*)&wp[kb * 8];
                float4 w1 = *(const float4*)&wp[kb * 8 + 4];
                acc += bf2f((unsigned short)dv[0]) * w0.x + bf2f((unsigned short)dv[1]) * w0.y
                     + bf2f((unsigned short)dv[2]) * w0.z + bf2f((unsigned short)dv[3]) * w0.w
                     + bf2f((unsigned short)dv[4]) * w1.x + bf2f((unsigned short)dv[5]) * w1.y
                     + bf2f((unsigned short)dv[6]) * w1.z + bf2f((unsigned short)dv[7]) * w1.w;
            }
            const float v1 = __shfl_xor(acc, 1);
            const float v2 = __shfl_xor(acc, 2);
            const float v3 = __shfl_xor(acc, 3);
            if (o == 0) {
                const float* f0 = states + (((size_t)t * NA + a) * NB + (b0 + row)) * NY + 4 * a;
                const float* f1 = states + (((size_t)(t + 1) * NA + a) * NB + (b0 + row)) * NY + 4 * a;
                const float mm0 = acc, mm1 = v1;
                const float s0 = softp(v2), s1 = softp(v3);
                const float x0 = f1[2], x1 = f1[3];
                const float t0 = (x0 - mm0) / s0, t1 = (x1 - mm1) / s1;
                accL += 0.5f * (t0 * t0 + t1 * t1 + 2.f * (__logf(s0) + __logf(s1)) + 2.f * LOG2PI);
                const float e0 = f0[0] + f0[2] * FSC - f1[0];
                const float e1 = f0[1] + f0[3] * FSC - f1[1];
                accEp += sqrtf(e0 * e0 + e1 * e1);
                const float g0 = mm0 - x0, g1 = mm1 - x1;
                accEv += sqrtf(g0 * g0 + g1 * g1);
            }
        }
    }

    // ---- final reduction: accs live in waves 0-3 (lanes with o==0) ----
    if (tid < 256) {
        float L = accL, E = accEp, V = accEv;
        #pragma unroll
        for (int off = 32; off; off >>= 1) {
            L += __shfl_down(L, off);
            E += __shfl_down(E, off);
            V += __shfl_down(V, off);
        }
        if ((tid & 63) == 0) {
            const float inv = 1.f / (float)(NT * NA);
            atomicAdd(&out[0], L * inv);
            atomicAdd(&out[1], E * inv);
            atomicAdd(&out[2], V * inv);
        }
    }
}

extern "C" void kernel_launch(void* const* d_in, const int* in_sizes, int n_in,
                              void* d_out, int out_size, void* d_ws, size_t ws_size,
                              hipStream_t stream) {
    const float* states = (const float*)d_in[0];
    const float* w_ih   = (const float*)d_in[1];
    const float* w_hh   = (const float*)d_in[2];
    const float* b_ih   = (const float*)d_in[3];
    const float* b_hh   = (const float*)d_in[4];
    const float* d1_w   = (const float*)d_in[5];
    const float* d1_b   = (const float*)d_in[6];
    const float* d2_w   = (const float*)d_in[7];
    const float* d2_b   = (const float*)d_in[8];
    const float* m_w    = (const float*)d_in[9];
    const float* m_b    = (const float*)d_in[10];
    const float* s_w    = (const float*)d_in[11];
    const float* s_b    = (const float*)d_in[12];

    int* ctrl = (int*)d_ws;                       // [0..7] xcd counters, [16..175] claim flags
    unsigned short* Wrz = (unsigned short*)((char*)d_ws + 1024);
    unsigned short* Wni = Wrz + (size_t)NA * 512 * K1;
    unsigned short* Wnh = Wni + (size_t)NA * 256 * K1;
    unsigned short* D1  = Wnh + (size_t)NA * 256 * NR;
    unsigned short* D2  = D1  + (size_t)NA * NH * NR;

    hipMemsetAsync(d_out, 0, 3 * sizeof(float), stream);
    hipMemsetAsync(d_ws, 0, 1024, stream);

    const int nrz = NA * 512 * K1;
    k_prep_wrz<<<(nrz + 255) / 256, 256, 0, stream>>>(w_ih, w_hh, Wrz);
    const int nni = NA * 256 * K1;
    k_prep_wni<<<(nni + 255) / 256, 256, 0, stream>>>(w_ih, Wni);
    const int nnh = NA * 256 * NR;
    k_prep_wnh<<<(nnh + 255) / 256, 256, 0, stream>>>(w_hh, Wnh);
    const int nd1 = NA * NH * NR;
    k_convert<<<(nd1 + 255) / 256, 256, 0, stream>>>(d1_w, D1, nd1);
    const int nd2 = NA * NH * NH;
    k_convert<<<(nd2 + 255) / 256, 256, 0, stream>>>(d2_w, D2, nd2);

    k_main<<<dim3(160), dim3(1024), 0, stream>>>(states, Wrz, Wni, Wnh, D1, D2,
                                                 b_ih, b_hh, d1_b, d2_b,
                                                 m_w, m_b, s_w, s_b, ctrl, (float*)d_out);
}